// Round 2
// baseline (193.279 us; speedup 1.0000x reference)
//
#include <hip/hip_runtime.h>

// Instant-NGP hash-grid trilinear interpolation — 2 threads per point.
// pts: (N,3) f32 in [0,1)^3; voxel_features: (buckets, 8) f32; out: (N, 8) f32.
//
// Lane pairing trick: thread t handles point i = t>>1, half h = t&1 (16 B of
// the 32 B feature row). Lanes 2k and 2k+1 gather the two halves of the SAME
// row -> same 64 B cache line -> the TA coalesces the pair into one L1
// request. This halves TCP request-processing vs 1-thread-per-point (which
// had 64 distinct lines per gather instruction), which is the hypothesized
// bottleneck (observed 0.27 line-req/cycle/CU, VALUBusy 3.5%).

__global__ __launch_bounds__(256) void ngp_hash_interp2(
    const float* __restrict__ pts,
    const float4* __restrict__ feat4,   // feature table viewed as float4[buckets*2]
    float4* __restrict__ out4,          // output viewed as float4[N*2]
    int N, unsigned buckets, int is_pow2)
{
    int t = blockIdx.x * blockDim.x + threadIdx.x;
    int i = t >> 1;          // point index
    unsigned h = (unsigned)(t & 1);  // which 16B half of the 32B row
    if (i >= N) return;

    float px = pts[3 * i + 0];
    float py = pts[3 * i + 1];
    float pz = pts[3 * i + 2];

    // f32 divide (matches jnp pts / RES rounding, keeps floor() consistent).
    float qx = px / 0.005f;
    float qy = py / 0.005f;
    float qz = pz / 0.005f;

    float bx = floorf(qx), by = floorf(qy), bz = floorf(qz);
    float fx = qx - bx, fy = qy - by, fz = qz - bz;

    unsigned ux = (unsigned)(int)bx;
    unsigned uy = (unsigned)(int)by;
    unsigned uz = (unsigned)(int)bz;

    unsigned hx0 = ux;                     // * PRIMES[0] == 1
    unsigned hx1 = ux + 1u;
    unsigned hy0 = uy * 2654435761u;       // PRIMES[1], uint32 wraparound
    unsigned hy1 = (uy + 1u) * 2654435761u;
    unsigned hz0 = uz * 805459861u;        // PRIMES[2]
    unsigned hz1 = (uz + 1u) * 805459861u;

    // Corner order x-fastest: c&1 = x, (c>>1)&1 = y, (c>>2)&1 = z
    unsigned hsh[8] = {
        hx0 ^ hy0 ^ hz0,
        hx1 ^ hy0 ^ hz0,
        hx0 ^ hy1 ^ hz0,
        hx1 ^ hy1 ^ hz0,
        hx0 ^ hy0 ^ hz1,
        hx1 ^ hy0 ^ hz1,
        hx0 ^ hy1 ^ hz1,
        hx1 ^ hy1 ^ hz1,
    };

    // 32-bit float4-element offsets (table is 128 MB -> fits 32-bit byte offset,
    // lets the compiler use SGPR-base + 32-bit voffset addressing: 1 VGPR/addr).
    unsigned off[8];
    if (is_pow2) {
        unsigned mask = buckets - 1u;
        #pragma unroll
        for (int c = 0; c < 8; ++c) off[c] = (hsh[c] & mask) * 2u + h;
    } else {
        #pragma unroll
        for (int c = 0; c < 8; ++c) off[c] = (hsh[c] % buckets) * 2u + h;
    }

    // Issue all 8 gathers before consuming any -> 8 paired-line loads in flight.
    float4 f[8];
    #pragma unroll
    for (int c = 0; c < 8; ++c) f[c] = feat4[off[c]];

    float wx0 = 1.0f - fx, wx1 = fx;
    float wy0 = 1.0f - fy, wy1 = fy;
    float wz0 = 1.0f - fz, wz1 = fz;
    // Same multiply order as reference: (wx*wy)*wz
    float w[8] = {
        (wx0 * wy0) * wz0, (wx1 * wy0) * wz0,
        (wx0 * wy1) * wz0, (wx1 * wy1) * wz0,
        (wx0 * wy0) * wz1, (wx1 * wy0) * wz1,
        (wx0 * wy1) * wz1, (wx1 * wy1) * wz1,
    };

    float4 a = make_float4(0.f, 0.f, 0.f, 0.f);
    #pragma unroll
    for (int c = 0; c < 8; ++c) {   // k = 0..7 sequential, matches einsum order
        a.x += w[c] * f[c].x;
        a.y += w[c] * f[c].y;
        a.z += w[c] * f[c].z;
        a.w += w[c] * f[c].w;
    }

    // Consecutive threads write consecutive 16 B -> perfectly coalesced.
    out4[(size_t)i * 2u + h] = a;
}

extern "C" void kernel_launch(void* const* d_in, const int* in_sizes, int n_in,
                              void* d_out, int out_size, void* d_ws, size_t ws_size,
                              hipStream_t stream) {
    const float* pts  = (const float*)d_in[0];
    const float4* feat4 = (const float4*)d_in[1];
    float4* out4 = (float4*)d_out;

    int N = in_sizes[0] / 3;
    unsigned buckets = (unsigned)(in_sizes[1] / 8);
    int is_pow2 = ((buckets & (buckets - 1u)) == 0u) ? 1 : 0;

    const int block = 256;
    const long long total = 2LL * N;          // 2 threads per point
    const int grid = (int)((total + block - 1) / block);
    hipLaunchKernelGGL(ngp_hash_interp2, dim3(grid), dim3(block), 0, stream,
                       pts, feat4, out4, N, buckets, is_pow2);
}